// Round 1
// baseline (13029.863 us; speedup 1.0000x reference)
//
#include <hip/hip_runtime.h>
#include <hip/hip_bf16.h>

// N=64, T=1024, I=512, H=512, P=256. Folded recurrence (verified R2/R3):
//   W_q = W_ip @ W_p (W_ip = W_ih[:,512:768]); v_bp = b_p @ W_ip.T (t>=1 only)
//   W_big rows: [0:512)=Whh_r+Wq_r, [512:1024)=Whh_z+Wq_z, [1024:1536)=Wq_n, [1536:2048)=Whh_n
//   r = sig(gix_r + h.w0 + bihr + bhhr + vbp_r); z = sig(gix_z + h.w1 + bihz + bhhz + vbp_z)
//   g = tanh(gix_n + h.w2 + bihn + vbp_n + r*(h.w3 + bhhn)); h' = (1-z)g + z h
//   out_t = h_{t+1} @ W_p.T + b_p  (computed at step t+1 from the bf16 h broadcast)
//
// R4 redesign: 64 self-sufficient blocks. Each wave computes ITS OWN gi_x slice
// (x_t @ W_ix^T for its 16 rows x [r8|z8],[ni8|pad8] col tiles) into registers —
// the gix global buffer (402 MB HBM write + 402 MB read round-trip, per R3 PMC
// WRITE=660MB/FETCH=1.09GB decomposition) is eliminated, as are the 96 producer
// blocks. Cross-block traffic is ONLY Hbf (64 KB/step), moved via explicit
// sc0 sc1 (LLC write-through/read-through) + per-wave vmcnt drain + relaxed
// agent flags — no compiler release/acquire => no per-step buffer_wbl2/inv.
// Flat single-phase barrier over 64 flags (2 serial legs, was 4).

typedef short short8 __attribute__((ext_vector_type(8)));
typedef float f32x4 __attribute__((ext_vector_type(4)));

__device__ __forceinline__ unsigned short f2bf(float f) {
  __hip_bfloat16 h = __float2bfloat16(f);
  return *reinterpret_cast<unsigned short*>(&h);
}

// ---------- zero Hbf + flags + dead ----------
__global__ void k_zero(unsigned int* __restrict__ p, int n) {
  int i = blockIdx.x * 256 + threadIdx.x;
  if (i < n) p[i] = 0u;
}

// ---------- weight fold (verified R2/R3) ----------
__global__ void k_fold(const float* __restrict__ W_ih, const float* __restrict__ W_hh,
                       const float* __restrict__ W_p, const float* __restrict__ b_p,
                       float* __restrict__ W_big, float* __restrict__ v_bp) {
  int idx = blockIdx.x * 256 + threadIdx.x;   // 1536*512 total
  int i = idx >> 9;
  int j = idx & 511;
  const float* wip = W_ih + (long)i * 768 + 512;
  float q = 0.f;
  for (int k = 0; k < 256; ++k) q = fmaf(wip[k], W_p[k * 512 + j], q);
  if (i < 1024) {
    W_big[(long)i * 512 + j] = W_hh[(long)i * 512 + j] + q;
  } else {
    W_big[(long)i * 512 + j] = q;
    W_big[(long)(i + 512) * 512 + j] = W_hh[(long)i * 512 + j];
  }
  if (j == 0) {
    float s = 0.f;
    for (int k = 0; k < 256; ++k) s = fmaf(b_p[k], wip[k], s);
    v_bp[i] = s;
  }
}

// ---------- pack bf16 weights ----------
// Wr[64 blocks][3 tiles][16 c][512 k]: T0=[r8|z8], T1=[ni8|nh8], T2=[proj4|pad12]  (R3-proven map)
// Wxr[64 blocks][2 tiles][16 c][512 k]: x-path gi weights, T0=[r8|z8], T1=[ni8|pad8]
//   (rows from W_ih[:,0:512]: T0 c<8 -> row b*8+c (r), c>=8 -> 512+b*8+c-8 (z);
//    T1 c<8 -> 1024+b*8+c (n), c>=8 -> zero pad)
__global__ void k_pack(const float* __restrict__ W_big, const float* __restrict__ W_ih,
                       const float* __restrict__ W_p,
                       unsigned short* __restrict__ Wr, unsigned short* __restrict__ Wx) {
  long e = (long)blockIdx.x * 256 + threadIdx.x;   // 1,572,864 + 1,048,576 total
  if (e < 1572864) {
    int k = (int)(e & 511);
    int cc = (int)((e >> 9) & 15);
    int rest = (int)(e >> 13);        // 0..191
    int T = rest % 3, b = rest / 3;
    int j = b * 8 + (cc & 7);
    bool hi = cc >= 8;
    float v;
    if (T == 0)      v = W_big[(long)(hi ? 512 + j : j) * 512 + k];
    else if (T == 1) v = W_big[(long)(hi ? 1536 + j : 1024 + j) * 512 + k];
    else             v = (cc < 4) ? W_p[(long)(b * 4 + cc) * 512 + k] : 0.f;
    Wr[e] = f2bf(v);
  } else {
    long e2 = e - 1572864;            // [0, 1048576)
    int k = (int)(e2 & 511);
    int cc = (int)((e2 >> 9) & 15);
    int rest = (int)(e2 >> 13);       // 0..127
    int T = rest & 1, b = rest >> 1;
    float v = 0.f;
    if (T == 0) {
      int row = (cc < 8) ? (b * 8 + cc) : (512 + b * 8 + (cc - 8));
      v = W_ih[(long)row * 768 + k];
    } else if (cc < 8) {
      v = W_ih[(long)(1024 + b * 8 + cc) * 768 + k];
    }
    Wx[e2] = f2bf(v);
  }
}

// ---------- persistent kernel: 64 homogeneous recurrent blocks ----------
__global__ __launch_bounds__(256, 1) void k_persist(
    const float* __restrict__ x,              // [64][1024][512] fp32
    const unsigned short* __restrict__ Wr, const unsigned short* __restrict__ Wxr,
    const float* __restrict__ b_ih, const float* __restrict__ b_hh,
    const float* __restrict__ v_bp, const float* __restrict__ b_p,
    unsigned short* __restrict__ Hbf,         // [2][64][512] bf16 (slot0 zeroed)
    float* __restrict__ out,                  // [64][1024][256]
    unsigned int* __restrict__ flags,         // 64 flags, 16-dword spacing
    unsigned int* __restrict__ dead) {
  const int tid = threadIdx.x;
  const int b = blockIdx.x;
  const int w = tid >> 6, lane = tid & 63, c = lane & 15, q = lane >> 4;
  const int j0 = b * 8, n0 = w * 16, jj = j0 + (c & 7), pcol = b * 4 + (c & 3);

  __shared__ unsigned short wxl[32 * 528];    // Wxr slice, pad 528 (4-way max on reads)

  // B-frags resident in VGPRs/AGPRs (192 regs)
  short8 wr0[16], wr1[16], wr2[16];
#pragma unroll
  for (int ki = 0; ki < 16; ++ki) {
    wr0[ki] = *(const short8*)(Wr + (((long)(b * 3 + 0) * 16 + c) * 512 + ki * 32 + q * 8));
    wr1[ki] = *(const short8*)(Wr + (((long)(b * 3 + 1) * 16 + c) * 512 + ki * 32 + q * 8));
    wr2[ki] = *(const short8*)(Wr + (((long)(b * 3 + 2) * 16 + c) * 512 + ki * 32 + q * 8));
  }
  // stage this block's x-weight slice (32 rows x 512) into LDS, 8 threads/row
  {
    const unsigned short* src = Wxr + (long)b * 16384;
    int row = tid >> 3, ch = tid & 7;
#pragma unroll
    for (int i = 0; i < 8; ++i) {
      int col = ch * 64 + i * 8;
      *(short8*)&wxl[row * 528 + col] = *(const short8*)(src + row * 512 + col);
    }
  }

  const float bihr = b_ih[jj],        bhhr = b_hh[jj],        vbr = v_bp[jj];
  const float bihz = b_ih[512 + jj],  bhhz = b_hh[512 + jj],  vbz = v_bp[512 + jj];
  const float bihn = b_ih[1024 + jj], bhhn = b_hh[1024 + jj], vbn = v_bp[1024 + jj];
  const float bp = b_p[pcol];
  float hprev[4] = {0.f, 0.f, 0.f, 0.f};
  f32x4 gp0{0.f, 0.f, 0.f, 0.f}, gp1 = gp0;   // this wave's gi_x slice, in registers
  bool alive = true;

  __syncthreads();   // wxl ready

  // gi_x producer: rows n0..n0+16 of x_tt, tiles [r8|z8],[ni8|pad8] for cols jj.
  // Plain cached loads (x is read-only), MFMA layout identical to consumer's.
  auto produce = [&](int tt) {
    f32x4 p0{0.f, 0.f, 0.f, 0.f}, p1 = p0;
    const float* xr = x + ((long)(n0 + c) * 1024 + tt) * 512 + q * 8;
#pragma unroll
    for (int ki = 0; ki < 16; ++ki) {
      float4 f0 = *(const float4*)(xr + ki * 32);
      float4 f1 = *(const float4*)(xr + ki * 32 + 4);
      short8 ax;
      ax[0] = f2bf(f0.x); ax[1] = f2bf(f0.y); ax[2] = f2bf(f0.z); ax[3] = f2bf(f0.w);
      ax[4] = f2bf(f1.x); ax[5] = f2bf(f1.y); ax[6] = f2bf(f1.z); ax[7] = f2bf(f1.w);
      short8 b0 = *(const short8*)&wxl[c * 528 + ki * 32 + q * 8];
      short8 b1 = *(const short8*)&wxl[(16 + c) * 528 + ki * 32 + q * 8];
      p0 = __builtin_amdgcn_mfma_f32_16x16x32_bf16(ax, b0, p0, 0, 0, 0);
      p1 = __builtin_amdgcn_mfma_f32_16x16x32_bf16(ax, b1, p1, 0, 0, 0);
    }
    gp0 = p0; gp1 = p1;
  };

  produce(0);

  for (int t = 0; t <= 1024; ++t) {
    const int cur = t & 1;
    // ---- Hbf A-frags: one batched LLC-coherent load, single vmcnt drain ----
    const unsigned short* hb = Hbf + (long)cur * 32768 + (long)(n0 + c) * 512 + q * 8;
    short8 h0, h1, h2, h3, h4, h5, h6, h7, h8, h9, hA, hB, hC, hD, hE, hF;
    asm volatile(
        "global_load_dwordx4 %[o0], %[a], off sc0 sc1\n\t"
        "global_load_dwordx4 %[o1], %[a], off offset:64 sc0 sc1\n\t"
        "global_load_dwordx4 %[o2], %[a], off offset:128 sc0 sc1\n\t"
        "global_load_dwordx4 %[o3], %[a], off offset:192 sc0 sc1\n\t"
        "global_load_dwordx4 %[o4], %[a], off offset:256 sc0 sc1\n\t"
        "global_load_dwordx4 %[o5], %[a], off offset:320 sc0 sc1\n\t"
        "global_load_dwordx4 %[o6], %[a], off offset:384 sc0 sc1\n\t"
        "global_load_dwordx4 %[o7], %[a], off offset:448 sc0 sc1\n\t"
        "global_load_dwordx4 %[o8], %[a], off offset:512 sc0 sc1\n\t"
        "global_load_dwordx4 %[o9], %[a], off offset:576 sc0 sc1\n\t"
        "global_load_dwordx4 %[oA], %[a], off offset:640 sc0 sc1\n\t"
        "global_load_dwordx4 %[oB], %[a], off offset:704 sc0 sc1\n\t"
        "global_load_dwordx4 %[oC], %[a], off offset:768 sc0 sc1\n\t"
        "global_load_dwordx4 %[oD], %[a], off offset:832 sc0 sc1\n\t"
        "global_load_dwordx4 %[oE], %[a], off offset:896 sc0 sc1\n\t"
        "global_load_dwordx4 %[oF], %[a], off offset:960 sc0 sc1\n\t"
        "s_waitcnt vmcnt(0)"
        : [o0]"=&v"(h0), [o1]"=&v"(h1), [o2]"=&v"(h2), [o3]"=&v"(h3),
          [o4]"=&v"(h4), [o5]"=&v"(h5), [o6]"=&v"(h6), [o7]"=&v"(h7),
          [o8]"=&v"(h8), [o9]"=&v"(h9), [oA]"=&v"(hA), [oB]"=&v"(hB),
          [oC]"=&v"(hC), [oD]"=&v"(hD), [oE]"=&v"(hE), [oF]"=&v"(hF)
        : [a]"v"(hb)
        : "memory");

    f32x4 a0{0.f, 0.f, 0.f, 0.f}, a1 = a0, a2 = a0;
#define RK(H, K)                                                          \
    a0 = __builtin_amdgcn_mfma_f32_16x16x32_bf16(H, wr0[K], a0, 0, 0, 0); \
    a1 = __builtin_amdgcn_mfma_f32_16x16x32_bf16(H, wr1[K], a1, 0, 0, 0); \
    a2 = __builtin_amdgcn_mfma_f32_16x16x32_bf16(H, wr2[K], a2, 0, 0, 0);
    RK(h0, 0)  RK(h1, 1)  RK(h2, 2)  RK(h3, 3)
    RK(h4, 4)  RK(h5, 5)  RK(h6, 6)  RK(h7, 7)
    RK(h8, 8)  RK(h9, 9)  RK(hA, 10) RK(hB, 11)
    RK(hC, 12) RK(hD, 13) RK(hE, 14) RK(hF, 15)
#undef RK

    if (t >= 1 && c < 4) {
#pragma unroll
      for (int r = 0; r < 4; ++r)
        out[((long)(n0 + q * 4 + r) * 1024 + (t - 1)) * 256 + pcol] = a2[r] + bp;
    }
    if (t == 1024) break;

    // ---- gates: s = h-part + in-reg gi_x part; shfl partner carries z / nh ----
    const float cR = t ? (bihr + bhhr + vbr) : (bihr + bhhr);
    const float cZ = t ? (bihz + bhhz + vbz) : (bihz + bhhz);
    const float cN = t ? (bihn + vbn) : bihn;
    float s0x[4], s1x[4];
#pragma unroll
    for (int r = 0; r < 4; ++r) { s0x[r] = a0[r] + gp0[r]; s1x[r] = a1[r] + gp1[r]; }
    unsigned short* hw = Hbf + (long)(cur ^ 1) * 32768 + (long)(n0 + q * 4) * 512 + jj;
#pragma unroll
    for (int r = 0; r < 4; ++r) {
      float ps0 = __shfl_xor(s0x[r], 8);   // partner z total (h+x parts; gp1 pad=0 for nh)
      float ps1 = __shfl_xor(s1x[r], 8);   // partner nh (h-part only, x pad is zero)
      if (c < 8) {
        float rr = __builtin_amdgcn_rcpf(1.f + __expf(-(s0x[r] + cR)));
        float zz = __builtin_amdgcn_rcpf(1.f + __expf(-(ps0 + cZ)));
        float aa = s1x[r] + cN + rr * (ps1 + bhhn);
        float gg = 1.f - 2.f * __builtin_amdgcn_rcpf(1.f + __expf(2.f * aa)); // tanh, inf-safe
        float hn = (1.f - zz) * gg + zz * hprev[r];
        hprev[r] = hn;
        unsigned short hv = f2bf(hn);
        unsigned short* pr = hw + r * 512;
        asm volatile("global_store_short %0, %1, off sc0 sc1" :: "v"(pr), "v"(hv) : "memory");
      }
    }

    // ---- publish: every wave drains its write-through stores, then one flag ----
    asm volatile("s_waitcnt vmcnt(0)" ::: "memory");
    __syncthreads();
    const unsigned int rnd = (unsigned int)t + 1u;
    if (tid == 0 && alive)
      __hip_atomic_store(&flags[b * 16], rnd, __ATOMIC_RELAXED, __HIP_MEMORY_SCOPE_AGENT);

    // ---- gi_x for t+1 — hidden under the barrier wait ----
    if (t < 1023) produce(t + 1);

    // ---- flat barrier: wave 0 lanes each poll one flag ----
    if (tid < 64 && alive) {
      int spins = 0;
      while (__hip_atomic_load(&flags[tid * 16], __ATOMIC_RELAXED,
                               __HIP_MEMORY_SCOPE_AGENT) < rnd) {
        __builtin_amdgcn_s_sleep(1);
        if ((++spins & 2047) == 0) {
          if (__hip_atomic_load(dead, __ATOMIC_RELAXED, __HIP_MEMORY_SCOPE_AGENT)) {
            alive = false; break;
          }
          if (spins > 1000000) {
            __hip_atomic_store(dead, 1u, __ATOMIC_RELAXED, __HIP_MEMORY_SCOPE_AGENT);
            alive = false; break;
          }
        }
      }
    }
    __syncthreads();
  }
}

extern "C" void kernel_launch(void* const* d_in, const int* in_sizes, int n_in,
                              void* d_out, int out_size, void* d_ws, size_t ws_size,
                              hipStream_t stream) {
  const float* x    = (const float*)d_in[0];
  // d_in[1] = text_lengths (all == T; unused)
  const float* W_ih = (const float*)d_in[2];
  const float* W_hh = (const float*)d_in[3];
  const float* b_ih = (const float*)d_in[4];
  const float* b_hh = (const float*)d_in[5];
  const float* W_p  = (const float*)d_in[6];
  const float* b_p  = (const float*)d_in[7];
  float* out = (float*)d_out;

  // workspace layout (bytes), total ~9.6 MB
  constexpr size_t OFF_WBIG = 0;           // 2048*512*4     = 4,194,304
  constexpr size_t OFF_VBP  = 4194304;     // 1536*4 -> pad 8,192
  constexpr size_t OFF_WR   = 4202496;     // 64*3*16*512*2  = 3,145,728
  constexpr size_t OFF_WXR  = 7348224;     // 64*2*16*512*2  = 2,097,152
  constexpr size_t OFF_HBF  = 9445376;     // 2*64*512*2     = 131,072
  constexpr size_t OFF_FLG  = 9576448;     // 64*64          = 4,096
  constexpr size_t OFF_DEAD = 9580544;     // 64
  constexpr size_t WS_NEED  = 9580608;
  if (ws_size < WS_NEED) return;   // zero out -> absmax == max|ref| flags this

  char* ws = (char*)d_ws;
  float* W_big        = (float*)(ws + OFF_WBIG);
  float* v_bp         = (float*)(ws + OFF_VBP);
  unsigned short* Wr  = (unsigned short*)(ws + OFF_WR);
  unsigned short* Wxr = (unsigned short*)(ws + OFF_WXR);
  unsigned short* Hbf = (unsigned short*)(ws + OFF_HBF);
  unsigned int* flags = (unsigned int*)(ws + OFF_FLG);
  unsigned int* dead  = (unsigned int*)(ws + OFF_DEAD);

  // zero Hbf + flags + dead (contiguous from OFF_HBF): 33,808 uints
  k_zero<<<133, 256, 0, stream>>>((unsigned int*)(ws + OFF_HBF), 33808);
  k_fold<<<3072, 256, 0, stream>>>(W_ih, W_hh, W_p, b_p, W_big, v_bp);
  k_pack<<<10240, 256, 0, stream>>>(W_big, W_ih, W_p, Wr, Wxr);
  k_persist<<<64, 256, 0, stream>>>(x, Wr, Wxr, b_ih, b_hh, v_bp, b_p,
                                    Hbf, out, flags, dead);
}

// Round 2
// 12673.373 us; speedup vs baseline: 1.0281x; 1.0281x over previous
//
#include <hip/hip_runtime.h>
#include <hip/hip_bf16.h>

// N=64, T=1024, I=512, H=512, P=256. Folded recurrence (verified R2/R3):
//   W_q = W_ip @ W_p (W_ip = W_ih[:,512:768]); v_bp = b_p @ W_ip.T (t>=1 only)
//   W_big rows: [0:512)=Whh_r+Wq_r, [512:1024)=Whh_z+Wq_z, [1024:1536)=Wq_n, [1536:2048)=Whh_n
//   r = sig(gix_r + h.w0 + bihr + bhhr + vbp_r); z = sig(gix_z + h.w1 + bihz + bhhz + vbp_z)
//   g = tanh(gix_n + h.w2 + bihn + vbp_n + r*(h.w3 + bhhn)); h' = (1-z)g + z h
//   out_t = h_{t+1} @ W_p.T + b_p  (computed at step t+1 from the tagged h broadcast)
//
// R5: TAGGED-DATA SYNC. R4 post-mortem: all traffic predictions landed (WRITE
// 660->264 MB, conflicts -500x) but dur was flat at ~12.6 us/step -> the cost
// is ~4 serialized cross-XCD coherence legs (h' drain, flag store, flag detect,
// h load), each ~2-3 us. R5 removes the flag machinery entirely: Hd holds
// dwords (tag<<16)|bf16(h); producers fire sc0sc1 dword stores (no drain) and
// consumers poll the data itself (re-issue 16-load batch until all tags == t).
// Dword stores are single-copy atomic -> each value carries its own validity.
// Waves are fully independent (wave w consumes only peer waves w) -> zero
// per-step __syncthreads. Flow control by induction on the 2-slot ping-pong.

typedef short short8 __attribute__((ext_vector_type(8)));
typedef float f32x4 __attribute__((ext_vector_type(4)));
typedef unsigned int u32x4 __attribute__((ext_vector_type(4)));

__device__ __forceinline__ unsigned short f2bf(float f) {
  __hip_bfloat16 h = __float2bfloat16(f);
  return *reinterpret_cast<unsigned short*>(&h);
}

// ---------- zero Hd + dead ----------
__global__ void k_zero(unsigned int* __restrict__ p, int n) {
  int i = blockIdx.x * 256 + threadIdx.x;
  if (i < n) p[i] = 0u;
}

// ---------- weight fold (verified R2/R3) ----------
__global__ void k_fold(const float* __restrict__ W_ih, const float* __restrict__ W_hh,
                       const float* __restrict__ W_p, const float* __restrict__ b_p,
                       float* __restrict__ W_big, float* __restrict__ v_bp) {
  int idx = blockIdx.x * 256 + threadIdx.x;   // 1536*512 total
  int i = idx >> 9;
  int j = idx & 511;
  const float* wip = W_ih + (long)i * 768 + 512;
  float q = 0.f;
  for (int k = 0; k < 256; ++k) q = fmaf(wip[k], W_p[k * 512 + j], q);
  if (i < 1024) {
    W_big[(long)i * 512 + j] = W_hh[(long)i * 512 + j] + q;
  } else {
    W_big[(long)i * 512 + j] = q;
    W_big[(long)(i + 512) * 512 + j] = W_hh[(long)i * 512 + j];
  }
  if (j == 0) {
    float s = 0.f;
    for (int k = 0; k < 256; ++k) s = fmaf(b_p[k], wip[k], s);
    v_bp[i] = s;
  }
}

// ---------- pack bf16 weights (unchanged, verified R4) ----------
// Wr[64 blocks][3 tiles][16 c][512 k]: T0=[r8|z8], T1=[ni8|nh8], T2=[proj4|pad12]
// Wxr[64 blocks][2 tiles][16 c][512 k]: x-path gi weights, T0=[r8|z8], T1=[ni8|pad8]
__global__ void k_pack(const float* __restrict__ W_big, const float* __restrict__ W_ih,
                       const float* __restrict__ W_p,
                       unsigned short* __restrict__ Wr, unsigned short* __restrict__ Wx) {
  long e = (long)blockIdx.x * 256 + threadIdx.x;   // 1,572,864 + 1,048,576 total
  if (e < 1572864) {
    int k = (int)(e & 511);
    int cc = (int)((e >> 9) & 15);
    int rest = (int)(e >> 13);        // 0..191
    int T = rest % 3, b = rest / 3;
    int j = b * 8 + (cc & 7);
    bool hi = cc >= 8;
    float v;
    if (T == 0)      v = W_big[(long)(hi ? 512 + j : j) * 512 + k];
    else if (T == 1) v = W_big[(long)(hi ? 1536 + j : 1024 + j) * 512 + k];
    else             v = (cc < 4) ? W_p[(long)(b * 4 + cc) * 512 + k] : 0.f;
    Wr[e] = f2bf(v);
  } else {
    long e2 = e - 1572864;            // [0, 1048576)
    int k = (int)(e2 & 511);
    int cc = (int)((e2 >> 9) & 15);
    int rest = (int)(e2 >> 13);       // 0..127
    int T = rest & 1, b = rest >> 1;
    float v = 0.f;
    if (T == 0) {
      int row = (cc < 8) ? (b * 8 + cc) : (512 + b * 8 + (cc - 8));
      v = W_ih[(long)row * 768 + k];
    } else if (cc < 8) {
      v = W_ih[(long)(1024 + b * 8 + cc) * 768 + k];
    }
    Wx[e2] = f2bf(v);
  }
}

// ---------- persistent kernel: 64 blocks, 256 waves, data-tag sync ----------
__global__ __launch_bounds__(256, 1) void k_persist(
    const float* __restrict__ x,              // [64][1024][512] fp32
    const unsigned short* __restrict__ Wr, const unsigned short* __restrict__ Wxr,
    const float* __restrict__ b_ih, const float* __restrict__ b_hh,
    const float* __restrict__ v_bp, const float* __restrict__ b_p,
    unsigned int* __restrict__ Hd,            // [2][64 rows][512 cols] tagged dwords
    float* __restrict__ out,                  // [64][1024][256]
    unsigned int* __restrict__ dead) {
  const int tid = threadIdx.x;
  const int b = blockIdx.x;
  const int w = tid >> 6, lane = tid & 63, c = lane & 15, q = lane >> 4;
  const int j0 = b * 8, n0 = w * 16, jj = j0 + (c & 7), pcol = b * 4 + (c & 3);

  __shared__ unsigned short wxl[32 * 528];    // Wxr slice, pad 528

  // B-frags resident in registers
  short8 wr0[16], wr1[16], wr2[16];
#pragma unroll
  for (int ki = 0; ki < 16; ++ki) {
    wr0[ki] = *(const short8*)(Wr + (((long)(b * 3 + 0) * 16 + c) * 512 + ki * 32 + q * 8));
    wr1[ki] = *(const short8*)(Wr + (((long)(b * 3 + 1) * 16 + c) * 512 + ki * 32 + q * 8));
    wr2[ki] = *(const short8*)(Wr + (((long)(b * 3 + 2) * 16 + c) * 512 + ki * 32 + q * 8));
  }
  // stage this block's x-weight slice (32 rows x 512) into LDS, 8 threads/row
  {
    const unsigned short* src = Wxr + (long)b * 16384;
    int row = tid >> 3, ch = tid & 7;
#pragma unroll
    for (int i = 0; i < 8; ++i) {
      int col = ch * 64 + i * 8;
      *(short8*)&wxl[row * 528 + col] = *(const short8*)(src + row * 512 + col);
    }
  }

  const float bihr = b_ih[jj],        bhhr = b_hh[jj],        vbr = v_bp[jj];
  const float bihz = b_ih[512 + jj],  bhhz = b_hh[512 + jj],  vbz = v_bp[512 + jj];
  const float bihn = b_ih[1024 + jj], bhhn = b_hh[1024 + jj], vbn = v_bp[1024 + jj];
  const float bp = b_p[pcol];
  float hprev[4] = {0.f, 0.f, 0.f, 0.f};
  f32x4 gp0{0.f, 0.f, 0.f, 0.f}, gp1 = gp0;   // this wave's gi_x slice, in registers
  bool alive = true;

  __syncthreads();   // wxl ready (only barrier in the whole kernel)

  // gi_x producer: rows n0..n0+16 of x_tt, tiles [r8|z8],[ni8|pad8] for cols jj.
  auto produce = [&](int tt) {
    f32x4 p0{0.f, 0.f, 0.f, 0.f}, p1 = p0;
    const float* xr = x + ((long)(n0 + c) * 1024 + tt) * 512 + q * 8;
#pragma unroll
    for (int ki = 0; ki < 16; ++ki) {
      float4 f0 = *(const float4*)(xr + ki * 32);
      float4 f1 = *(const float4*)(xr + ki * 32 + 4);
      short8 ax;
      ax[0] = f2bf(f0.x); ax[1] = f2bf(f0.y); ax[2] = f2bf(f0.z); ax[3] = f2bf(f0.w);
      ax[4] = f2bf(f1.x); ax[5] = f2bf(f1.y); ax[6] = f2bf(f1.z); ax[7] = f2bf(f1.w);
      short8 b0 = *(const short8*)&wxl[c * 528 + ki * 32 + q * 8];
      short8 b1 = *(const short8*)&wxl[(16 + c) * 528 + ki * 32 + q * 8];
      p0 = __builtin_amdgcn_mfma_f32_16x16x32_bf16(ax, b0, p0, 0, 0, 0);
      p1 = __builtin_amdgcn_mfma_f32_16x16x32_bf16(ax, b1, p1, 0, 0, 0);
    }
    gp0 = p0; gp1 = p1;
  };

  produce(0);

  // 16x dwordx4 batched LLC load: ki pair at ki*128B and ki*128B+16
#define LOAD16(BASE)                                                        \
  asm volatile(                                                             \
      "global_load_dwordx4 %[o0], %[a], off sc0 sc1\n\t"                    \
      "global_load_dwordx4 %[o1], %[a], off offset:16 sc0 sc1\n\t"          \
      "global_load_dwordx4 %[o2], %[a], off offset:128 sc0 sc1\n\t"         \
      "global_load_dwordx4 %[o3], %[a], off offset:144 sc0 sc1\n\t"         \
      "global_load_dwordx4 %[o4], %[a], off offset:256 sc0 sc1\n\t"         \
      "global_load_dwordx4 %[o5], %[a], off offset:272 sc0 sc1\n\t"         \
      "global_load_dwordx4 %[o6], %[a], off offset:384 sc0 sc1\n\t"         \
      "global_load_dwordx4 %[o7], %[a], off offset:400 sc0 sc1\n\t"         \
      "global_load_dwordx4 %[o8], %[a], off offset:512 sc0 sc1\n\t"         \
      "global_load_dwordx4 %[o9], %[a], off offset:528 sc0 sc1\n\t"         \
      "global_load_dwordx4 %[oA], %[a], off offset:640 sc0 sc1\n\t"         \
      "global_load_dwordx4 %[oB], %[a], off offset:656 sc0 sc1\n\t"         \
      "global_load_dwordx4 %[oC], %[a], off offset:768 sc0 sc1\n\t"         \
      "global_load_dwordx4 %[oD], %[a], off offset:784 sc0 sc1\n\t"         \
      "global_load_dwordx4 %[oE], %[a], off offset:896 sc0 sc1\n\t"         \
      "global_load_dwordx4 %[oF], %[a], off offset:912 sc0 sc1\n\t"         \
      "s_waitcnt vmcnt(0)"                                                  \
      : [o0]"=&v"(d0), [o1]"=&v"(d1), [o2]"=&v"(d2), [o3]"=&v"(d3),         \
        [o4]"=&v"(d4), [o5]"=&v"(d5), [o6]"=&v"(d6), [o7]"=&v"(d7),         \
        [o8]"=&v"(d8), [o9]"=&v"(d9), [oA]"=&v"(dA), [oB]"=&v"(dB),         \
        [oC]"=&v"(dC), [oD]"=&v"(dD), [oE]"=&v"(dE), [oF]"=&v"(dF)          \
      : [a]"v"(BASE)                                                        \
      : "memory")

#define ORT(DD) acc |= (DD.x ^ texp) | (DD.y ^ texp) | (DD.z ^ texp) | (DD.w ^ texp)

  // poll until every tag == t (stale => tag bits differ => acc>>16 != 0)
#define POLL16(BASE)                                                        \
  { int spins = 0;                                                          \
    for (;;) {                                                              \
      LOAD16(BASE);                                                         \
      unsigned int acc = 0;                                                 \
      ORT(d0); ORT(d1); ORT(d2); ORT(d3); ORT(d4); ORT(d5); ORT(d6); ORT(d7);\
      ORT(d8); ORT(d9); ORT(dA); ORT(dB); ORT(dC); ORT(dD); ORT(dE); ORT(dF);\
      if (!__any((int)(acc >> 16))) break;                                  \
      if ((++spins & 63) == 0) {                                            \
        if (__hip_atomic_load(dead, __ATOMIC_RELAXED, __HIP_MEMORY_SCOPE_AGENT)) { \
          alive = false; break;                                             \
        }                                                                   \
        if (spins > 200000) {                                               \
          __hip_atomic_store(dead, 1u, __ATOMIC_RELAXED, __HIP_MEMORY_SCOPE_AGENT); \
          alive = false; break;                                             \
        }                                                                   \
      }                                                                     \
    }                                                                       \
  }

  // pack 8 tagged dwords (DA=cols+0..3, DB=cols+4..7) -> bf16 A-frag, 3 MFMA
#define PACK2(HI, LO) __builtin_amdgcn_perm((HI), (LO), 0x05040100u)
#define PKMFMA(DA, DB, K)                                                   \
  { u32x4 pw;                                                               \
    pw.x = PACK2(DA.y, DA.x); pw.y = PACK2(DA.w, DA.z);                     \
    pw.z = PACK2(DB.y, DB.x); pw.w = PACK2(DB.w, DB.z);                     \
    short8 ah = __builtin_bit_cast(short8, pw);                             \
    a0 = __builtin_amdgcn_mfma_f32_16x16x32_bf16(ah, wr0[K], a0, 0, 0, 0);  \
    a1 = __builtin_amdgcn_mfma_f32_16x16x32_bf16(ah, wr1[K], a1, 0, 0, 0);  \
    a2 = __builtin_amdgcn_mfma_f32_16x16x32_bf16(ah, wr2[K], a2, 0, 0, 0); }

  for (int t = 0; t <= 1024; ++t) {
    const int cur = t & 1;
    const unsigned int texp = ((unsigned int)t) << 16;
    const unsigned int* hp = Hd + (long)cur * 32768 + (long)(n0 + c) * 512 + q * 8;

    f32x4 a0{0.f, 0.f, 0.f, 0.f}, a1 = a0, a2 = a0;
    u32x4 d0, d1, d2, d3, d4, d5, d6, d7, d8, d9, dA, dB, dC, dD, dE, dF;

    POLL16(hp);                         // half A: ki 0..7
    if (!alive) break;
    PKMFMA(d0, d1, 0)  PKMFMA(d2, d3, 1)  PKMFMA(d4, d5, 2)  PKMFMA(d6, d7, 3)
    PKMFMA(d8, d9, 4)  PKMFMA(dA, dB, 5)  PKMFMA(dC, dD, 6)  PKMFMA(dE, dF, 7)

    POLL16(hp + 256);                   // half B: ki 8..15
    if (!alive) break;
    PKMFMA(d0, d1, 8)  PKMFMA(d2, d3, 9)  PKMFMA(d4, d5, 10) PKMFMA(d6, d7, 11)
    PKMFMA(d8, d9, 12) PKMFMA(dA, dB, 13) PKMFMA(dC, dD, 14) PKMFMA(dE, dF, 15)

    if (t >= 1 && c < 4) {
#pragma unroll
      for (int r = 0; r < 4; ++r)
        out[((long)(n0 + q * 4 + r) * 1024 + (t - 1)) * 256 + pcol] = a2[r] + bp;
    }
    if (t == 1024) break;

    // ---- gates: s = h-part + in-reg gi_x part; shfl partner carries z / nh ----
    const float cR = t ? (bihr + bhhr + vbr) : (bihr + bhhr);
    const float cZ = t ? (bihz + bhhz + vbz) : (bihz + bhhz);
    const float cN = t ? (bihn + vbn) : bihn;
    float s0x[4], s1x[4];
#pragma unroll
    for (int r = 0; r < 4; ++r) { s0x[r] = a0[r] + gp0[r]; s1x[r] = a1[r] + gp1[r]; }
    unsigned int* hw = Hd + (long)(cur ^ 1) * 32768 + (long)(n0 + q * 4) * 512 + jj;
    const unsigned int tg = ((unsigned int)(t + 1)) << 16;
#pragma unroll
    for (int r = 0; r < 4; ++r) {
      float ps0 = __shfl_xor(s0x[r], 8);   // partner z total
      float ps1 = __shfl_xor(s1x[r], 8);   // partner nh (h-part; x pad is zero)
      if (c < 8) {
        float rr = __builtin_amdgcn_rcpf(1.f + __expf(-(s0x[r] + cR)));
        float zz = __builtin_amdgcn_rcpf(1.f + __expf(-(ps0 + cZ)));
        float aa = s1x[r] + cN + rr * (ps1 + bhhn);
        float gg = 1.f - 2.f * __builtin_amdgcn_rcpf(1.f + __expf(2.f * aa)); // tanh
        float hn = (1.f - zz) * gg + zz * hprev[r];
        hprev[r] = hn;
        unsigned int hv = tg | (unsigned int)f2bf(hn);
        const unsigned int* pr = hw + r * 512;
        asm volatile("global_store_dword %0, %1, off sc0 sc1" :: "v"(pr), "v"(hv) : "memory");
      }
    }
    // no drain, no flag, no __syncthreads: the tagged data IS the flag.
    // gi_x for t+1 overlaps our stores' flight + peers' skew.
    if (t < 1023) produce(t + 1);
  }
#undef LOAD16
#undef ORT
#undef POLL16
#undef PACK2
#undef PKMFMA
}

extern "C" void kernel_launch(void* const* d_in, const int* in_sizes, int n_in,
                              void* d_out, int out_size, void* d_ws, size_t ws_size,
                              hipStream_t stream) {
  const float* x    = (const float*)d_in[0];
  // d_in[1] = text_lengths (all == T; unused)
  const float* W_ih = (const float*)d_in[2];
  const float* W_hh = (const float*)d_in[3];
  const float* b_ih = (const float*)d_in[4];
  const float* b_hh = (const float*)d_in[5];
  const float* W_p  = (const float*)d_in[6];
  const float* b_p  = (const float*)d_in[7];
  float* out = (float*)d_out;

  // workspace layout (bytes), total ~9.7 MB
  constexpr size_t OFF_WBIG = 0;           // 2048*512*4     = 4,194,304
  constexpr size_t OFF_VBP  = 4194304;     // 1536*4 -> pad 8,192
  constexpr size_t OFF_WR   = 4202496;     // 64*3*16*512*2  = 3,145,728
  constexpr size_t OFF_WXR  = 7348224;     // 64*2*16*512*2  = 2,097,152
  constexpr size_t OFF_HD   = 9445376;     // 2*64*512*4     = 262,144
  constexpr size_t OFF_DEAD = 9707520;     // 64
  constexpr size_t WS_NEED  = 9707584;
  if (ws_size < WS_NEED) return;   // zero out -> absmax == max|ref| flags this

  char* ws = (char*)d_ws;
  float* W_big        = (float*)(ws + OFF_WBIG);
  float* v_bp         = (float*)(ws + OFF_VBP);
  unsigned short* Wr  = (unsigned short*)(ws + OFF_WR);
  unsigned short* Wxr = (unsigned short*)(ws + OFF_WXR);
  unsigned int* Hd    = (unsigned int*)(ws + OFF_HD);
  unsigned int* dead  = (unsigned int*)(ws + OFF_DEAD);

  // zero Hd + dead: 65552 dwords
  k_zero<<<257, 256, 0, stream>>>((unsigned int*)(ws + OFF_HD), 65552);
  k_fold<<<3072, 256, 0, stream>>>(W_ih, W_hh, W_p, b_p, W_big, v_bp);
  k_pack<<<10240, 256, 0, stream>>>(W_big, W_ih, W_p, Wr, Wxr);
  k_persist<<<64, 256, 0, stream>>>(x, Wr, Wxr, b_ih, b_hh, v_bp, b_p,
                                    Hd, out, dead);
}